// Round 14
// baseline (2337.751 us; speedup 1.0000x reference)
//
#include <hip/hip_runtime.h>

#define KM 29
#define GTAB 2048

typedef __bf16 bf16_t;
typedef __bf16 bf16x8 __attribute__((ext_vector_type(8)));
typedef __bf16 bf16x2 __attribute__((ext_vector_type(2)));
typedef float  f32x4  __attribute__((ext_vector_type(4)));
typedef float  f32x2  __attribute__((ext_vector_type(2)));

__device__ __forceinline__ float silu_f(float x){ return x / (1.0f + __expf(-x)); }

__device__ __forceinline__ float wave_reduce_sum(float v){
  #pragma unroll
  for (int s = 1; s < 64; s <<= 1) v += __shfl_xor(v, s);
  return v;
}

__device__ __forceinline__ constexpr int LOF2(int k){
  return (k<1)?0 : (k<4)?1 : (k<9)?2 : (k<14)?3 : (k<19)?4 : (k<24)?5 : 6;
}

__device__ __forceinline__ f32x4 mfma16(bf16x8 a, bf16x8 b, f32x4 c){
  return __builtin_amdgcn_mfma_f32_16x16x32_bf16(a, b, c, 0, 0, 0);
}

__device__ __forceinline__ float env_f(float d){
  float xx = d*(1.0f/12.0f);
  float x2 = xx*xx, x4 = x2*x2, x5 = x4*xx;
  float env = 1.0f - 21.0f*x5 + 35.0f*x5*xx - 15.0f*x5*x2;
  return (xx < 1.0f) ? env : 0.0f;
}

// ---------------- CSR build ----------------
__global__ void k_count(const int* __restrict__ EI, int* __restrict__ cnt, int E){
  int e = blockIdx.x*256 + threadIdx.x;
  if (e < E) atomicAdd(&cnt[EI[E+e]], 1);
}

__global__ __launch_bounds__(1024) void k_scan(int* __restrict__ cnt, int* __restrict__ rowptr, int N){
  __shared__ int ts[1024];
  int t = threadIdx.x;
  int base = t*8;
  int loc[8]; int sum = 0;
  #pragma unroll
  for (int u = 0; u < 8; u++){ int idx = base+u; int v = (idx < N) ? cnt[idx] : 0; loc[u] = sum; sum += v; }
  ts[t] = sum; __syncthreads();
  for (int off = 1; off < 1024; off <<= 1){
    int v = (t >= off) ? ts[t-off] : 0;
    __syncthreads();
    ts[t] += v;
    __syncthreads();
  }
  int excl = ts[t] - sum;
  #pragma unroll
  for (int u = 0; u < 8; u++){
    int idx = base+u;
    if (idx < N){ int r = excl + loc[u]; rowptr[idx] = r; cnt[idx] = r; }
  }
  if (t == 1023) rowptr[N] = ts[1023];
}

__global__ void k_fill(const int* __restrict__ EI, int* __restrict__ cur, int* __restrict__ order, int E){
  int e = blockIdx.x*256 + threadIdx.x;
  if (e < E){ int pos = atomicAdd(&cur[EI[E+e]], 1); order[pos] = e; }
}

__global__ void k_sort(const int* __restrict__ rowptr, int* __restrict__ order, int N){
  int n = blockIdx.x*256 + threadIdx.x;
  if (n >= N) return;
  int rp = rowptr[n], re = rowptr[n+1];
  for (int a = rp+1; a < re; a++){
    int key = order[a]; int b = a-1;
    while (b >= rp && order[b] > key){ order[b+1] = order[b]; b--; }
    order[b+1] = key;
  }
}

// ---------------- weight transposes ----------------
__global__ void k_tr(const float* __restrict__ src, bf16_t* __restrict__ dst,
                     int L, int R, int C, int Lstr){
  int idx = blockIdx.x*256 + threadIdx.x;
  int total = L*R*C;
  if (idx >= total) return;
  int l = idx / (R*C); int rem = idx - l*(R*C);
  int r = rem / C; int c = rem - r*C;
  dst[((size_t)l*C + c)*R + r] = (bf16_t)src[(size_t)l*Lstr + (size_t)r*C + c];
}

__global__ void k_tr2(const float* __restrict__ src, bf16_t* __restrict__ dst){
  int idx = blockIdx.x*256 + threadIdx.x;
  if (idx >= 4*128*128) return;
  int l = idx >> 14; int j = (idx >> 7) & 127; int c = idx & 127;
  float v = (j < 64) ? src[(size_t)l*16384 + c*64 + j]
                     : src[(size_t)l*16384 + 8192 + c*64 + (j-64)];
  dst[idx] = (bf16_t)v;
}

// ---------------- radial MLP table build ----------------
__global__ __launch_bounds__(256) void k_tab_embed(
    const float* __restrict__ We0, const float* __restrict__ be0,
    const float* __restrict__ We1, const float* __restrict__ be1,
    const float* __restrict__ Wr0, const float* __restrict__ Wr1, const float* __restrict__ Wrl,
    float* __restrict__ h2tab, float* __restrict__ radtab)
{
  __shared__ float sb[4][640];
  const int wid = threadIdx.x >> 6, lane = threadIdx.x & 63;
  const int e = blockIdx.x*4 + wid;
  if (e >= GTAB) return;
  const float d = e * (12.0f/(GTAB-1));
  const float DLT = 12.0f/599.0f;
  const float CO  = -0.5f/((2.0f*DLT)*(2.0f*DLT));
  int jc = (int)(d/DLT + 0.5f);
  int j0 = jc - 16; if (j0 < 0) j0 = 0; if (j0 > 600-32) j0 = 600-32;
  float diff = d - (float)(j0+lane)*DLT;
  float gval = __expf(CO*diff*diff);
  float p[10];
  #pragma unroll
  for (int u = 0; u < 10; u++) p[u] = 0.f;
  const int c2 = 2*lane;
  for (int jj = 0; jj < 32; jj++){
    float gj = __shfl(gval, jj);
    int row = j0 + jj;
    const float2 w0 = *(const float2*)(We0 + row*128 + c2);
    p[0] += gj*w0.x; p[1] += gj*w0.y;
    #pragma unroll
    for (int i = 0; i < 4; i++){
      const float2 wr = *(const float2*)(Wr0 + ((size_t)i*600 + row)*128 + c2);
      p[2+2*i] += gj*wr.x; p[3+2*i] += gj*wr.y;
    }
  }
  sb[wid][c2]   = silu_f(p[0] + be0[c2]);
  sb[wid][c2+1] = silu_f(p[1] + be0[c2+1]);
  #pragma unroll
  for (int i = 0; i < 4; i++){
    sb[wid][128 + 128*i + c2]   = silu_f(p[2+2*i]);
    sb[wid][128 + 128*i + c2+1] = silu_f(p[3+2*i]);
  }
  float a0 = 0.f, a1 = 0.f;
  for (int c = 0; c < 128; c++){
    float hv = sb[wid][c];
    const float2 w = *(const float2*)(We1 + c*128 + c2);
    a0 += hv*w.x; a1 += hv*w.y;
  }
  a0 = silu_f(a0 + be1[c2]); a1 = silu_f(a1 + be1[c2+1]);
  h2tab[(size_t)e*128 + c2]     = a0;
  h2tab[(size_t)e*128 + c2 + 1] = a1;
  #pragma unroll
  for (int i = 0; i < 4; i++){
    float r0 = 0.f, r1 = 0.f;
    const float* W1 = Wr1 + (size_t)i*128*128;
    for (int c = 0; c < 128; c++){
      float rv = sb[wid][128 + 128*i + c];
      const float2 w = *(const float2*)(W1 + c*128 + c2);
      r0 += rv*w.x; r1 += rv*w.y;
    }
    r0 = silu_f(r0); r1 = silu_f(r1);
    const float* Wl = Wrl + (size_t)i*128*7;
    float pl[7];
    #pragma unroll
    for (int l = 0; l < 7; l++) pl[l] = r0*Wl[c2*7+l] + r1*Wl[(c2+1)*7+l];
    #pragma unroll
    for (int l = 0; l < 7; l++) pl[l] = wave_reduce_sum(pl[l]);
    if (lane == 0){
      #pragma unroll
      for (int l = 0; l < 7; l++) radtab[(size_t)e*28 + i*7 + l] = pl[l];
    }
  }
}

// ---------------- per-node h2 sum with inline interp ----------------
__global__ __launch_bounds__(256) void k_h2sum(
    const float* __restrict__ ed, const float* __restrict__ h2tab,
    const int* __restrict__ rowptr, const int* __restrict__ order,
    bf16_t* __restrict__ h2sum, int N)
{
  int n = blockIdx.x*2 + (threadIdx.x >> 7);
  int ch = threadIdx.x & 127;
  if (n >= N) return;
  int rp = rowptr[n], deg = rowptr[n+1] - rp;
  float acc = 0.f;
  for (int idx = 0; idx < deg; idx++){
    int e = order[rp+idx];
    float d = ed[e];
    float u = d * ((GTAB-1)/12.0f);
    int j = (int)u; if (j > GTAB-2) j = GTAB-2;
    float f = u - (float)j;
    float a = h2tab[(size_t)j*128 + ch], b = h2tab[(size_t)(j+1)*128 + ch];
    acc += a + f*(b-a);
  }
  h2sum[(size_t)n*128 + ch] = (bf16_t)acc;
}

// ---------------- x init (MFMA from h2sum) ----------------
__global__ __launch_bounds__(256) void k_init_x(
    const int* __restrict__ Z, const float* __restrict__ emb,
    const bf16_t* __restrict__ WeprojT, const bf16_t* __restrict__ h2sum,
    bf16_t* __restrict__ Xb, int N)
{
  __shared__ bf16_t h2s[32*136];
  __shared__ int Zs[32];
  int n0 = blockIdx.x*32, t = threadIdx.x;
  for (int idx = t; idx < 32*128; idx += 256){
    int nn = idx >> 7, ch = idx & 127;
    int n = n0 + nn;
    h2s[nn*136 + ch] = (n < N) ? h2sum[(size_t)n*128 + ch] : (bf16_t)0.f;
  }
  if (t < 32) Zs[t] = (n0 + t < N) ? Z[n0+t] : 0;
  __syncthreads();
  int wid = t >> 6, lane = t & 63;
  int mtile = wid & 1;
  int row = mtile*16 + (lane & 15);
  int koff = (lane >> 4)*8;
  bf16x8 afr[4];
  #pragma unroll
  for (int kk = 0; kk < 4; kk++) afr[kk] = *(const bf16x8*)(h2s + row*136 + kk*32 + koff);
  for (int nt = (wid>>1); nt < 232; nt += 2){
    f32x4 acc = {0.f,0.f,0.f,0.f};
    int col = nt*16 + (lane & 15);
    #pragma unroll
    for (int kk = 0; kk < 4; kk++){
      bf16x8 b = *(const bf16x8*)(WeprojT + (size_t)col*128 + kk*32 + koff);
      acc = mfma16(afr[kk], b, acc);
    }
    #pragma unroll
    for (int r = 0; r < 4; r++){
      int r32 = mtile*16 + (lane>>4)*4 + r;
      int n = n0 + r32;
      if (n < N){
        float v = acc[r] * (1.0f/23.395238876342773f);
        if (col < 128) v += emb[(size_t)Zs[r32]*128 + col];
        Xb[(size_t)n*3712 + col] = (bf16_t)v;
      }
    }
  }
}

// ---------------- layer-0 pqv: rms + combined [P|Q] GEMM + PV8/QV8 + P0/Q0 ----------------
__global__ __launch_bounds__(512) void k_pqv(
    const bf16_t* __restrict__ Xb, const float* __restrict__ gamma1,
    const bf16_t* __restrict__ WmsgCT, const bf16_t* __restrict__ WvT,
    unsigned char* __restrict__ PV8, unsigned char* __restrict__ QV8,
    float* __restrict__ P0, float* __restrict__ Q0, int layer)
{
  __shared__ bf16_t ys16[32*136];
  __shared__ bf16_t pq16[32*136];
  int n = blockIdx.x, t = threadIdx.x;
  int wid = t >> 6, lane = t & 63;
  const float* g1 = gamma1 + layer*128;
  const bf16_t* xp = Xb + (size_t)n*3712;
  for (int k = wid; k < KM; k += 8){
    float x0 = (float)xp[k*128 + lane], x1 = (float)xp[k*128 + 64 + lane];
    float ss = wave_reduce_sum(x0*x0 + x1*x1);
    float sc = rsqrtf(ss*(1.0f/128.0f) + 1e-6f);
    ys16[k*136 + lane]      = (bf16_t)(x0*sc*g1[lane]);
    ys16[k*136 + 64 + lane] = (bf16_t)(x1*sc*g1[64+lane]);
  }
  for (int idx = t; idx < 3*136; idx += 512) ys16[29*136 + idx] = (bf16_t)0.f;
  __syncthreads();
  int mtile = wid >> 2;
  int row = mtile*16 + (lane & 15);
  int koff = (lane >> 4)*8;
  {
    const bf16_t* Bc = WmsgCT + (size_t)layer*16384;
    f32x4 acc[2] = {{0,0,0,0},{0,0,0,0}};
    #pragma unroll
    for (int kk = 0; kk < 128; kk += 32){
      bf16x8 a = *(const bf16x8*)(ys16 + row*136 + kk + koff);
      #pragma unroll
      for (int u = 0; u < 2; u++){
        int col = ((wid&3)*2+u)*16 + (lane & 15);
        bf16x8 b = *(const bf16x8*)(Bc + (size_t)col*128 + kk + koff);
        acc[u] = mfma16(a, b, acc[u]);
      }
    }
    #pragma unroll
    for (int u = 0; u < 2; u++){
      int col = ((wid&3)*2+u)*16 + (lane & 15);
      #pragma unroll
      for (int r = 0; r < 4; r++){
        int r32 = mtile*16 + (lane>>4)*4 + r;
        pq16[r32*136 + col] = (bf16_t)acc[u][r];
      }
      if (mtile == 0 && (lane>>4) == 0){
        float v = acc[u][0];
        if (col < 64) P0[(size_t)n*64 + col] = v;
        else          Q0[(size_t)n*64 + col - 64] = v;
      }
    }
  }
  __syncthreads();
  {
    const bf16_t* Bt = WvT + (size_t)layer*8192;
    f32x4 accP[2] = {{0,0,0,0},{0,0,0,0}};
    f32x4 accQ[2] = {{0,0,0,0},{0,0,0,0}};
    #pragma unroll
    for (int kk = 0; kk < 64; kk += 32){
      bf16x8 aP = *(const bf16x8*)(pq16 + row*136 + kk + koff);
      bf16x8 aQ = *(const bf16x8*)(pq16 + row*136 + 64 + kk + koff);
      #pragma unroll
      for (int u = 0; u < 2; u++){
        int col = ((wid&3)*2+u)*16 + (lane & 15);
        bf16x8 b = *(const bf16x8*)(Bt + (size_t)col*64 + kk + koff);
        accP[u] = mfma16(aP, b, accP[u]);
        accQ[u] = mfma16(aQ, b, accQ[u]);
      }
    }
    unsigned char* pvp = PV8 + (size_t)n*4096;
    unsigned char* qvp = QV8 + (size_t)n*4096;
    int r0i = mtile*16 + (lane>>4)*4;
    #pragma unroll
    for (int u = 0; u < 2; u++){
      int col = ((wid&3)*2+u)*16 + (lane & 15);
      float pk[4], qk[4];
      #pragma unroll
      for (int r = 0; r < 4; r++){
        int r32 = r0i + r;
        pk[r] = (r32 < KM) ? accP[u][r] : 0.f;
        qk[r] = (r32 < KM) ? accQ[u][r] : 0.f;
      }
      int dw = __builtin_amdgcn_cvt_pk_fp8_f32(pk[0], pk[1], 0, false);
      dw = __builtin_amdgcn_cvt_pk_fp8_f32(pk[2], pk[3], dw, true);
      *(unsigned int*)(pvp + col*32 + r0i) = (unsigned int)dw;
      int dw2 = __builtin_amdgcn_cvt_pk_fp8_f32(qk[0], qk[1], 0, false);
      dw2 = __builtin_amdgcn_cvt_pk_fp8_f32(qk[2], qk[3], dw2, true);
      *(unsigned int*)(qvp + col*32 + r0i) = (unsigned int)dw2;
    }
  }
}

// ---------------- per-layer: edge logits + gate (MFMA); emits expat + radl ----------------
__global__ __launch_bounds__(256) void k_edge_logits(
    const int* __restrict__ EI, const float* __restrict__ ed,
    const float* __restrict__ P0, const float* __restrict__ Q0,
    const float* __restrict__ radtab, const bf16_t* __restrict__ WapT, const float* __restrict__ wa,
    const bf16_t* __restrict__ WgT, float* __restrict__ expat, float* __restrict__ radl,
    bf16_t* __restrict__ gate16, int E, int layer)
{
  __shared__ bf16_t m0s[16*72];
  __shared__ int   srcs[16], tgts[16];
  __shared__ float r0s[16];
  __shared__ float envs[16];
  int t = threadIdx.x;
  int eb = blockIdx.x*16;
  if (t < 16){
    int e = eb + t;
    if (e < E){
      srcs[t] = EI[e]; tgts[t] = EI[E+e];
      float d = ed[e];
      envs[t] = env_f(d);
      float u = d * ((GTAB-1)/12.0f);
      int j = (int)u; if (j > GTAB-2) j = GTAB-2;
      float f = u - (float)j;
      #pragma unroll
      for (int l = 0; l < 7; l++){
        float a = radtab[(size_t)j*28 + layer*7 + l], b = radtab[(size_t)(j+1)*28 + layer*7 + l];
        float rv = a + f*(b-a);
        radl[(size_t)e*7 + l] = rv;
        if (l == 0) r0s[t] = rv;
      }
    } else { srcs[t] = 0; tgts[t] = 0; r0s[t] = 0.f; envs[t] = 0.f; }
  }
  __syncthreads();
  #pragma unroll
  for (int u = 0; u < 4; u++){
    int idx = t + u*256;
    int i = idx >> 6, j = idx & 63;
    m0s[i*72 + j] = (bf16_t)((P0[(size_t)srcs[i]*64 + j] + Q0[(size_t)tgts[i]*64 + j]) * r0s[i]);
  }
  __syncthreads();
  int wid = t >> 6, lane = t & 63;
  int l15 = lane & 15, lg = lane >> 4;
  int koff = lg*8;
  bf16x8 a0 = *(const bf16x8*)(m0s + l15*72 + koff);
  bf16x8 a1 = *(const bf16x8*)(m0s + l15*72 + 32 + koff);
  const bf16_t* Ba = WapT + (size_t)layer*16384;
  const bf16_t* Bg = WgT  + (size_t)layer*8192;
  const float* wav = wa + layer*256;
  f32x4 accA[4], accG[2];
  #pragma unroll
  for (int u = 0; u < 4; u++){
    int col = 64*wid + u*16 + l15;
    f32x4 acc = {0,0,0,0};
    acc = mfma16(a0, *(const bf16x8*)(Ba + (size_t)col*64 + koff), acc);
    acc = mfma16(a1, *(const bf16x8*)(Ba + (size_t)col*64 + 32 + koff), acc);
    accA[u] = acc;
  }
  #pragma unroll
  for (int u = 0; u < 2; u++){
    int col = 32*wid + u*16 + l15;
    f32x4 acc = {0,0,0,0};
    acc = mfma16(a0, *(const bf16x8*)(Bg + (size_t)col*64 + koff), acc);
    acc = mfma16(a1, *(const bf16x8*)(Bg + (size_t)col*64 + 32 + koff), acc);
    accG[u] = acc;
  }
  #pragma unroll
  for (int u = 0; u < 2; u++){
    int col = 32*wid + u*16 + l15;
    #pragma unroll
    for (int r = 0; r < 4; r++){
      int e = eb + lg*4 + r;
      if (e < E) gate16[(size_t)e*128 + col] = (bf16_t)silu_f(accG[u][r]);
    }
  }
  #pragma unroll
  for (int hpair = 0; hpair < 2; hpair++){
    int c0 = 64*wid + hpair*32 + l15;
    float w0 = wav[c0], w1 = wav[c0+16];
    float s[4];
    #pragma unroll
    for (int r = 0; r < 4; r++)
      s[r] = silu_f(accA[2*hpair][r])*w0 + silu_f(accA[2*hpair+1][r])*w1;
    #pragma unroll
    for (int r = 0; r < 4; r++){
      s[r] += __shfl_xor(s[r], 1);
      s[r] += __shfl_xor(s[r], 2);
      s[r] += __shfl_xor(s[r], 4);
      s[r] += __shfl_xor(s[r], 8);
    }
    if (l15 == 0){
      #pragma unroll
      for (int r = 0; r < 4; r++){
        int e = eb + lg*4 + r;
        if (e < E) expat[(size_t)e*8 + 2*wid + hpair] = envs[lg*4 + r] * __expf(s[r]);
      }
    }
  }
}

// fp8 dword -> 4 fp32 FMA into acc
#define FMA_DW(dw, kb) { \
  f32x2 lo_ = __builtin_amdgcn_cvt_pk_f32_fp8((dw), false); \
  f32x2 hi_ = __builtin_amdgcn_cvt_pk_f32_fp8((dw), true); \
  acc[(kb)]   += lo_.x * rw[LOF2((kb))]; \
  acc[(kb)+1] += lo_.y * rw[LOF2((kb)+1)]; \
  acc[(kb)+2] += hi_.x * rw[LOF2((kb)+2)]; \
  acc[(kb)+3] += hi_.y * rw[LOF2((kb)+3)]; }

// ---------------- per-layer: gather-only kernel (1 node per block) ----------------
__global__ __launch_bounds__(512, 4) void k_gather(
    const int* __restrict__ EI, const int* __restrict__ rowptr, const int* __restrict__ order,
    const unsigned char* __restrict__ PV8, const unsigned char* __restrict__ QV8,
    const bf16_t* __restrict__ gate16, const float* __restrict__ expat,
    const float* __restrict__ radl,
    bf16_t* __restrict__ agg)
{
  __shared__ bf16_t mA[32*136];
  __shared__ bf16_t mB[32*136];
  __shared__ float at8[512];
  __shared__ float rl7[512];
  __shared__ int   esb[64], srcs[64];
  __shared__ float denl[32];

  int n = blockIdx.x, t = threadIdx.x;
  int rp = rowptr[n], deg = rowptr[n+1] - rp;
  if (deg == 0){
    for (int idx = t; idx < 3712; idx += 512) agg[(size_t)n*3712 + idx] = (bf16_t)0.f;
    return;
  }
  int eg = t >> 7, hv = t & 127, h = hv >> 4;
  float acc[32];
  #pragma unroll
  for (int j = 0; j < 32; j++) acc[j] = 0.f;
  float S[7];
  #pragma unroll
  for (int l = 0; l < 7; l++) S[l] = 0.f;
  float dpart = 0.f;
  for (int base = 0; base < deg; base += 64){
    int ne = min(64, deg - base);
    if (base > 0) __syncthreads();
    if (t < ne){ int e = order[rp + base + t]; esb[t] = e; srcs[t] = EI[e]; }
    __syncthreads();
    if (t < ne*8){
      int i = t >> 3, q = t & 7;
      int e = esb[i];
      at8[t] = expat[(size_t)e*8 + q];
      if (q < 7) rl7[t] = radl[(size_t)e*7 + q];
    }
    __syncthreads();
    uint4 A0 = {0,0,0,0}, A1 = {0,0,0,0}, B0 = {0,0,0,0}, B1 = {0,0,0,0};
    float gA = 0.f, gB = 0.f;
    int i = eg;
    if (i < ne){
      const uint4* p = (const uint4*)(PV8 + (size_t)srcs[i]*4096 + hv*32);
      A0 = p[0]; A1 = p[1];
      gA = (float)gate16[(size_t)esb[i]*128 + hv];
    }
    if (i + 4 < ne){
      const uint4* p = (const uint4*)(PV8 + (size_t)srcs[i+4]*4096 + hv*32);
      B0 = p[0]; B1 = p[1];
      gB = (float)gate16[(size_t)esb[i+4]*128 + hv];
    }
    while (i < ne){
      int i2 = i + 8;
      uint4 C0 = {0,0,0,0}, C1 = {0,0,0,0}; float gC = 0.f;
      if (i2 < ne){
        const uint4* p = (const uint4*)(PV8 + (size_t)srcs[i2]*4096 + hv*32);
        C0 = p[0]; C1 = p[1];
        gC = (float)gate16[(size_t)esb[i2]*128 + hv];
      }
      float ae = at8[i*8 + h];
      dpart += ae;
      float w = gA * ae;
      float rw[7];
      #pragma unroll
      for (int l = 0; l < 7; l++){ rw[l] = rl7[i*8 + l]*w; S[l] += rw[l]; }
      FMA_DW(A0.x, 0)  FMA_DW(A0.y, 4)  FMA_DW(A0.z, 8)  FMA_DW(A0.w, 12)
      FMA_DW(A1.x, 16) FMA_DW(A1.y, 20) FMA_DW(A1.z, 24) FMA_DW(A1.w, 28)
      A0 = B0; A1 = B1; gA = gB;
      B0 = C0; B1 = C1; gB = gC;
      i += 4;
    }
  }
  {
    const unsigned char* qvp = QV8 + (size_t)n*4096 + hv*32;
    uint4 q0 = *(const uint4*)qvp;
    uint4 q1 = *(const uint4*)(qvp + 16);
    float rw[7];
    #pragma unroll
    for (int l = 0; l < 7; l++) rw[l] = S[l];
    FMA_DW(q0.x, 0)  FMA_DW(q0.y, 4)  FMA_DW(q0.z, 8)  FMA_DW(q0.w, 12)
    FMA_DW(q1.x, 16) FMA_DW(q1.y, 20) FMA_DW(q1.z, 24) FMA_DW(q1.w, 28)
  }
  if ((hv & 15) == 0) denl[eg*8 + h] = dpart;
  __syncthreads();
  {
    float dsum = denl[h] + denl[8 + h] + denl[16 + h] + denl[24 + h];
    float inv = 1.0f/(dsum + 1e-30f);
    #pragma unroll
    for (int j = 0; j < 32; j++) acc[j] *= inv;
  }
  if (eg == 0){
    #pragma unroll
    for (int j = 0; j < 32; j++) mA[j*136 + hv] = (bf16_t)acc[j];
  } else if (eg == 1){
    #pragma unroll
    for (int j = 0; j < 32; j++) mB[j*136 + hv] = (bf16_t)acc[j];
  }
  __syncthreads();
  if (eg == 2){
    #pragma unroll
    for (int j = 0; j < 32; j++) mA[j*136 + hv] = (bf16_t)((float)mA[j*136 + hv] + acc[j]);
  } else if (eg == 3){
    #pragma unroll
    for (int j = 0; j < 32; j++) mB[j*136 + hv] = (bf16_t)((float)mB[j*136 + hv] + acc[j]);
  }
  __syncthreads();
  for (int idx = t; idx < 3712; idx += 512){
    int k = idx >> 7, c = idx & 127;
    agg[(size_t)n*3712 + idx] = (bf16_t)((float)mA[k*136 + c] + (float)mB[k*136 + c]);
  }
}

// ======== flat GEMM helpers: 4 nodes/block, 128-row padded tile, 256 threads ========

// coop load 4 nodes' [29][128] bf16 rows into aLDS[(node*32+k)*136], zero pads
__device__ __forceinline__ void flat_load(const bf16_t* __restrict__ src, bf16_t* aLDS,
                                          int n0, int N, int t){
  for (int p = t; p < 4*1856; p += 256){
    int node = p / 1856, rem = p - node*1856;   // rem in bf16x2 units
    int k = rem >> 6, cp = rem & 63;
    bf16x2 v; v.x = (bf16_t)0.f; v.y = (bf16_t)0.f;
    if (n0 + node < N) v = *(const bf16x2*)(src + (size_t)(n0+node)*3712 + k*128 + cp*2);
    *(bf16x2*)(aLDS + (node*32 + k)*136 + cp*2) = v;
  }
  for (int p = t; p < 4*3*136; p += 256){
    int node = p / 408, rem = p - node*408;
    aLDS[(node*32 + 29)*136 + rem] = (bf16_t)0.f;
  }
}

// ---------------- K_A: Wo GEMM + residual + rms(g2) + gate ----------------
__global__ __launch_bounds__(256, 4) void k_wo(
    bf16_t* __restrict__ agg,       // in: gather out; out: ys2 (in-place)
    const bf16_t* __restrict__ WoT, bf16_t* __restrict__ Xb,
    const float* __restrict__ gamma2, const float* __restrict__ Wfg,
    float* __restrict__ gfb, int layer, int N)
{
  __shared__ bf16_t aLDS[128*136];
  __shared__ bf16_t y0[4*128];
  int t = threadIdx.x, wid = t >> 6, lane = t & 63;
  int l15 = lane & 15, lg = lane >> 4, koff = lg*8;
  int n0 = blockIdx.x*4;

  flat_load(agg, aLDS, n0, N, t);
  __syncthreads();
  bf16x8 af[2][4];
  #pragma unroll
  for (int m = 0; m < 2; m++)
    #pragma unroll
    for (int kc = 0; kc < 4; kc++)
      af[m][kc] = *(const bf16x8*)(aLDS + (wid*32 + m*16 + l15)*136 + kc*32 + koff);
  __syncthreads();
  // load X over aLDS + GEMM
  flat_load(Xb, aLDS, n0, N, t);
  f32x4 C[2][8];
  #pragma unroll
  for (int m = 0; m < 2; m++)
    #pragma unroll
    for (int u = 0; u < 8; u++) C[m][u] = (f32x4){0,0,0,0};
  const bf16_t* Bt = WoT + (size_t)layer*16384;
  #pragma unroll
  for (int kc = 0; kc < 4; kc++){
    #pragma unroll
    for (int u = 0; u < 8; u++){
      int col = u*16 + l15;
      bf16x8 b = *(const bf16x8*)(Bt + (size_t)col*128 + kc*32 + koff);
      C[0][u] = mfma16(af[0][kc], b, C[0][u]);
      C[1][u] = mfma16(af[1][kc], b, C[1][u]);
    }
  }
  __syncthreads();
  // add X (LDS), write xnew bf16 in place
  #pragma unroll
  for (int m = 0; m < 2; m++)
    #pragma unroll
    for (int u = 0; u < 8; u++){
      int col = u*16 + l15;
      #pragma unroll
      for (int r = 0; r < 4; r++){
        int row = wid*32 + m*16 + lg*4 + r;
        float xn = (float)aLDS[row*136 + col] + C[m][u][r];
        aLDS[row*136 + col] = (bf16_t)xn;
      }
    }
  __syncthreads();
  // rms + stores
  const float* g2 = gamma2 + layer*128;
  for (int r32 = wid; r32 < 128; r32 += 4){
    int node = r32 >> 5, k = r32 & 31;
    if (k >= KM || n0 + node >= N) continue;
    float x0 = (float)aLDS[r32*136 + lane], x1 = (float)aLDS[r32*136 + 64 + lane];
    float ss = wave_reduce_sum(x0*x0 + x1*x1);
    float sc = rsqrtf(ss*(1.0f/128.0f) + 1e-6f);
    bf16_t yv0 = (bf16_t)(x0*sc*g2[lane]), yv1 = (bf16_t)(x1*sc*g2[64+lane]);
    size_t gb = (size_t)(n0+node)*3712 + k*128;
    Xb[gb + lane] = (bf16_t)x0; Xb[gb + 64 + lane] = (bf16_t)x1;
    agg[gb + lane] = yv0; agg[gb + 64 + lane] = yv1;
    if (k == 0){ y0[node*128 + lane] = yv0; y0[node*128 + 64 + lane] = yv1; }
  }
  __syncthreads();
  // gate
  const float* Wfgp = Wfg + (size_t)layer*16384;
  for (int p = t; p < 512; p += 256){
    int node = p >> 7, f = p & 127;
    if (n0 + node < N){
      float g = 0.f;
      for (int c = 0; c < 128; c++) g += (float)y0[node*128 + c]*Wfgp[c*128 + f];
      gfb[(size_t)(n0+node)*128 + f] = silu_f(g);
    }
  }
}

// ---------------- K_B: hs = (ys2 @ Wf1T) * gf ----------------
__global__ __launch_bounds__(256, 4) void k_wf1(
    bf16_t* __restrict__ ysb,       // in: ys2; out: hs (in-place)
    const float* __restrict__ gfb, const bf16_t* __restrict__ Wf1T, int layer, int N)
{
  __shared__ bf16_t aLDS[128*136];
  __shared__ float gfs[4*128];
  int t = threadIdx.x, wid = t >> 6, lane = t & 63;
  int l15 = lane & 15, lg = lane >> 4, koff = lg*8;
  int n0 = blockIdx.x*4;

  flat_load(ysb, aLDS, n0, N, t);
  for (int p = t; p < 512; p += 256){
    int node = p >> 7, f = p & 127;
    gfs[p] = (n0 + node < N) ? gfb[(size_t)(n0+node)*128 + f] : 0.f;
  }
  __syncthreads();
  bf16x8 af[2][4];
  #pragma unroll
  for (int m = 0; m < 2; m++)
    #pragma unroll
    for (int kc = 0; kc < 4; kc++)
      af[m][kc] = *(const bf16x8*)(aLDS + (wid*32 + m*16 + l15)*136 + kc*32 + koff);
  f32x4 C[2][8];
  #pragma unroll
  for (int m = 0; m < 2; m++)
    #pragma unroll
    for (int u = 0; u < 8; u++) C[m][u] = (f32x4){0,0,0,0};
  const bf16_t* Bt = Wf1T + (size_t)layer*16384;
  #pragma unroll
  for (int kc = 0; kc < 4; kc++){
    #pragma unroll
    for (int u = 0; u < 8; u++){
      int col = u*16 + l15;
      bf16x8 b = *(const bf16x8*)(Bt + (size_t)col*128 + kc*32 + koff);
      C[0][u] = mfma16(af[0][kc], b, C[0][u]);
      C[1][u] = mfma16(af[1][kc], b, C[1][u]);
    }
  }
  // write hs into own rows (wave-local: rows wid*32..wid*32+31)
  #pragma unroll
  for (int m = 0; m < 2; m++)
    #pragma unroll
    for (int u = 0; u < 8; u++){
      int col = u*16 + l15;
      float gfc = gfs[wid*128 + col];
      #pragma unroll
      for (int r = 0; r < 4; r++){
        int row = wid*32 + m*16 + lg*4 + r;
        aLDS[row*136 + col] = (bf16_t)(C[m][u][r]*gfc);
      }
    }
  __syncthreads();
  // coop store
  for (int p = t; p < 4*1856; p += 256){
    int node = p / 1856, rem = p - node*1856;
    int k = rem >> 6, cp = rem & 63;
    if (n0 + node < N)
      *(bf16x2*)(ysb + (size_t)(n0+node)*3712 + k*128 + cp*2) =
          *(const bf16x2*)(aLDS + (node*32 + k)*136 + cp*2);
  }
}

// ---------------- K_C: X += hs @ Wf2T; rms(g1next) -> ys1 ----------------
__global__ __launch_bounds__(256, 4) void k_wf2(
    bf16_t* __restrict__ hsb,       // in: hs; out: ys1 (in-place)
    const bf16_t* __restrict__ Wf2T, bf16_t* __restrict__ Xb,
    const float* __restrict__ gamma1, int layerNext, int do_ys1, int N)
{
  __shared__ bf16_t aLDS[128*136];
  int t = threadIdx.x, wid = t >> 6, lane = t & 63;
  int l15 = lane & 15, lg = lane >> 4, koff = lg*8;
  int n0 = blockIdx.x*4;

  flat_load(hsb, aLDS, n0, N, t);
  __syncthreads();
  bf16x8 af[2][4];
  #pragma unroll
  for (int m = 0; m < 2; m++)
    #pragma unroll
    for (int kc = 0; kc < 4; kc++)
      af[m][kc] = *(const bf16x8*)(aLDS + (wid*32 + m*16 + l15)*136 + kc*32 + koff);
  __syncthreads();
  flat_load(Xb, aLDS, n0, N, t);
  f32x4 C[2][8];
  #pragma unroll
  for (int m = 0; m < 2; m++)
    #pragma unroll
    for (int u = 0; u < 8; u++) C[m][u] = (f32x4){0,0,0,0};
  const bf16_t* Bt = Wf2T + (size_t)layerNext*16384 - 16384;   // layer = layerNext-1
  #pragma unroll
  for (int kc = 0; kc < 4; kc++){
    #pragma unroll
    for (int u = 0; u < 8; u++){
      int col = u*16 + l15;
      bf16x8 b = *(const bf16x8*)(Bt + (size_t)col*128 + kc*32 + koff);
      C[0][u] = mfma16(af[0][kc], b, C[0][u]);
      C[1][u] = mfma16(af[1][kc], b, C[1][u]);
    }
  }
  __syncthreads();
  #pragma unroll
  for (int m = 0; m < 2; m++)
    #pragma unroll
    for (int u = 0; u < 8; u++){
      int col = u*16 + l15;
      #pragma unroll
      for (int r = 0; r < 4; r++){
        int row = wid*32 + m*16 + lg*4 + r;
        float xn = (float)aLDS[row*136 + col] + C[m][u][r];
        aLDS[row*136 + col] = (bf16_t)xn;
      }
    }
  __syncthreads();
  const float* g1 = gamma1 + (size_t)layerNext*128;
  for (int r32 = wid; r32 < 128; r32 += 4){
    int node = r32 >> 5, k = r32 & 31;
    if (k >= KM || n0 + node >= N) continue;
    float x0 = (float)aLDS[r32*136 + lane], x1 = (float)aLDS[r32*136 + 64 + lane];
    size_t gb = (size_t)(n0+node)*3712 + k*128;
    Xb[gb + lane] = (bf16_t)x0; Xb[gb + 64 + lane] = (bf16_t)x1;
    if (do_ys1){
      float ss = wave_reduce_sum(x0*x0 + x1*x1);
      float sc = rsqrtf(ss*(1.0f/128.0f) + 1e-6f);
      hsb[gb + lane]      = (bf16_t)(x0*sc*g1[lane]);
      hsb[gb + 64 + lane] = (bf16_t)(x1*sc*g1[64+lane]);
    }
  }
}

// ---------------- K_D: pq = ys1 @ WmsgCT; P0/Q0; PV8/QV8 = pq @ WvT ----------------
__global__ __launch_bounds__(256, 4) void k_pqnext(
    const bf16_t* __restrict__ ysb,   // ys1
    const bf16_t* __restrict__ WmsgCT, const bf16_t* __restrict__ WvT,
    unsigned char* __restrict__ PV8, unsigned char* __restrict__ QV8,
    float* __restrict__ P0, float* __restrict__ Q0, int layerNext, int N)
{
  __shared__ bf16_t aLDS[128*136];
  int t = threadIdx.x, wid = t >> 6, lane = t & 63;
  int l15 = lane & 15, lg = lane >> 4, koff = lg*8;
  int n0 = blockIdx.x*4;

  flat_load(ysb, aLDS, n0, N, t);
  __syncthreads();
  bf16x8 af[2][4];
  #pragma unroll
  for (int m = 0; m < 2; m++)
    #pragma unroll
    for (int kc = 0; kc < 4; kc++)
      af[m][kc] = *(const bf16x8*)(aLDS + (wid*32 + m*16 + l15)*136 + kc*32 + koff);
  f32x4 C[2][8];
  #pragma unroll
  for (int m = 0; m < 2; m++)
    #pragma unroll
    for (int u = 0; u < 8; u++) C[m][u] = (f32x4){0,0,0,0};
  const bf16_t* Bc = WmsgCT + (size_t)layerNext*16384;
  #pragma unroll
  for (int kc = 0; kc < 4; kc++){
    #pragma unroll
    for (int u = 0; u < 8; u++){
      int col = u*16 + l15;
      bf16x8 b = *(const bf16x8*)(Bc + (size_t)col*128 + kc*32 + koff);
      C[0][u] = mfma16(af[0][kc], b, C[0][u]);
      C[1][u] = mfma16(af[1][kc], b, C[1][u]);
    }
  }
  // write pq into own rows + extract P0/Q0 (rows with k==0: m==0, lg==0, r==0)
  #pragma unroll
  for (int m = 0; m < 2; m++)
    #pragma unroll
    for (int u = 0; u < 8; u++){
      int col = u*16 + l15;
      #pragma unroll
      for (int r = 0; r < 4; r++){
        int row = wid*32 + m*16 + lg*4 + r;
        aLDS[row*136 + col] = (bf16_t)C[m][u][r];
      }
      if (m == 0 && lg == 0 && n0 + wid < N){
        float v = C[0][u][0];
        if (col < 64) P0[(size_t)(n0+wid)*64 + col] = v;
        else          Q0[(size_t)(n0+wid)*64 + col - 64] = v;
      }
    }
  __syncthreads();
  // PV: pq[:,0:64] @ WvT (K=64); QV: pq[:,64:128] @ WvT
  const bf16_t* Bt = WvT + (size_t)layerNext*8192;
  {
    bf16x8 ap[2][2];
    #pragma unroll
    for (int m = 0; m < 2; m++)
      #pragma unroll
      for (int kc = 0; kc < 2; kc++)
        ap[m][kc] = *(const bf16x8*)(aLDS + (wid*32 + m*16 + l15)*136 + kc*32 + koff);
    f32x4 P[2][8];
    #pragma unroll
    for (int m = 0; m < 2; m++)
      #pragma unroll
      for (int u = 0; u < 8; u++) P[m][u] = (f32x4){0,0,0,0};
    #pragma unroll
    for (int kc = 0; kc < 2; kc++){
      #pragma unroll
      for (int u = 0; u < 8; u++){
        int col = u*16 + l15;
        bf16x8 b = *(const bf16x8*)(Bt + (size_t)col*64 + kc*32 + koff);
        P[0][u] = mfma16(ap[0][kc], b, P[0][u]);
        P[1][u] = mfma16(ap[1][kc], b, P[1][u]);
      }
    }
    if (n0 + wid < N){
      unsigned char* pvp = PV8 + (size_t)(n0+wid)*4096;
      #pragma unroll
      for (int m = 0; m < 2; m++){
        int k0 = m*16 + lg*4;
        #pragma unroll
        for (int u = 0; u < 8; u++){
          int col = u*16 + l15;
          float pk[4];
          #pragma unroll
          for (int r = 0; r < 4; r++) pk[r] = (k0 + r < KM) ? P[m][u][r] : 0.f;
          int dw = __builtin_amdgcn_cvt_pk_fp8_f32(pk[0], pk[1], 0, false);
          dw = __builtin_amdgcn_cvt_pk_fp8_f32(pk[2], pk[3], dw, true);
          *(unsigned int*)(pvp + col*32 + k0) = (unsigned int)dw;
        }
      }
    }
  }
  {
    bf16x8 aq[2][2];
    #pragma unroll
    for (int m = 0; m < 2; m++)
      #pragma unroll
      for (int kc = 0; kc < 2; kc++)
        aq[m][kc] = *(const bf16x8*)(aLDS + (wid*32 + m*16 + l15)*136 + 64 + kc*32 + koff);
    f32x4 Qc[2][8];
    #pragma unroll
    for (int m = 0; m < 2; m++)
      #pragma unroll
      for (int u = 0; u < 8; u++) Qc[m][u] = (f32x4){0,0,0,0};
    #pragma unroll
    for (int kc = 0; kc < 2; kc++){
      #pragma unroll
      for (int u = 0; u < 8; u++){
        int col = u*16 + l15;
        bf16x8 b = *(const bf16x8*)(Bt + (size_t)col*64 + kc*32 + koff);
        Qc[0][u] = mfma16(aq[0][kc], b, Qc[0][u]);
        Qc[1][u] = mfma16(aq[1][kc], b, Qc[1][u]);
      }
    }
    if (n0 + wid < N){
      unsigned char* qvp = QV8 + (size_t)(n0+wid)*4096;
      #pragma unroll
      for (int m = 0; m < 2; m++){
        int k0 = m*16 + lg*4;
        #pragma unroll
        for (int u = 0; u < 8; u++){
          int col = u*16 + l15;
          float qk[4];
          #pragma unroll
          for (int r = 0; r < 4; r++) qk[r] = (k0 + r < KM) ? Qc[m][u][r] : 0.f;
          int dw2 = __builtin_amdgcn_cvt_pk_fp8_f32(qk[0], qk[1], 0, false);
          dw2 = __builtin_amdgcn_cvt_pk_fp8_f32(qk[2], qk[3], dw2, true);
          *(unsigned int*)(qvp + col*32 + k0) = (unsigned int)dw2;
        }
      }
    }
  }
}

// ---------------- output head ----------------
__global__ __launch_bounds__(256) void k_head(
    const bf16_t* __restrict__ Xb, const float* __restrict__ Wh1, const float* __restrict__ Wh2,
    float* __restrict__ partial, int N)
{
  __shared__ float wsum[4];
  int t = threadIdx.x;
  int half = t >> 7;
  int n = blockIdx.x*2 + half;
  int f = t & 127;
  float sv = 0.f;
  if (n < N){
    const bf16_t* xp = Xb + (size_t)n*3712;
    float acc = 0.f;
    for (int c = 0; c < 128; c++) acc += (float)xp[c]*Wh1[c*128 + f];
    sv = silu_f(acc)*Wh2[f];
  }
  sv = wave_reduce_sum(sv);
  if ((t & 63) == 0) wsum[t >> 6] = sv;
  __syncthreads();
  if (t == 0) partial[blockIdx.x] = wsum[0] + wsum[1] + wsum[2] + wsum[3];
}

__global__ __launch_bounds__(256) void k_reduce(const float* __restrict__ partial, float* __restrict__ out, int P){
  __shared__ float sh[256];
  int t = threadIdx.x;
  float s = 0.f;
  for (int i = t; i < P; i += 256) s += partial[i];
  sh[t] = s; __syncthreads();
  for (int off = 128; off > 0; off >>= 1){
    if (t < off) sh[t] += sh[t+off];
    __syncthreads();
  }
  if (t == 0) out[0] = sh[0] / 77.81317f;
}

extern "C" void kernel_launch(void* const* d_in, const int* in_sizes, int n_in,
                              void* d_out, int out_size, void* d_ws, size_t ws_size,
                              hipStream_t stream)
{
  const int*   Z      = (const int*)d_in[0];
  const int*   EI     = (const int*)d_in[1];
  const float* ed     = (const float*)d_in[2];
  const float* emb    = (const float*)d_in[3];
  const float* We0    = (const float*)d_in[4];
  const float* be0    = (const float*)d_in[5];
  const float* We1    = (const float*)d_in[6];
  const float* be1    = (const float*)d_in[7];
  const float* Weproj = (const float*)d_in[8];
  const float* gamma1 = (const float*)d_in[9];
  const float* gamma2 = (const float*)d_in[10];
  const float* Wr0    = (const float*)d_in[11];
  const float* Wr1    = (const float*)d_in[12];
  const float* Wrl    = (const float*)d_in[13];
  const float* Wmsg   = (const float*)d_in[14];
  const float* Wap    = (const float*)d_in[15];
  const float* wa     = (const float*)d_in[16];
  const float* Wg     = (const float*)d_in[17];
  const float* Wv     = (const float*)d_in[18];
  const float* Wo     = (const float*)d_in[19];
  const float* Wf1    = (const float*)d_in[20];
  const float* Wfg    = (const float*)d_in[21];
  const float* Wf2    = (const float*)d_in[22];
  const float* Wh1    = (const float*)d_in[23];
  const float* Wh2    = (const float*)d_in[24];

  const int N = in_sizes[0];
  const int E = in_sizes[2];

  float* ws = (float*)d_ws;
  size_t o = 0;
  auto alloc = [&](size_t nf){ float* p = ws + o; o += (nf + 7) & ~(size_t)7; return p; };

  bf16_t* Xb    = (bf16_t*)alloc((size_t)N*1856);      // N*3712 bf16
  float* P0     = alloc((size_t)N*64);
  float* Q0     = alloc((size_t)N*64);
  float* expat  = alloc((size_t)E*8);
  float* radl   = alloc((size_t)E*7);
  float* part   = alloc((size_t)((N+1)/2) + 8);
  float* radtab = alloc((size_t)GTAB*28);
  float* h2tab  = alloc((size_t)GTAB*128);
  bf16_t* h2sum = (bf16_t*)alloc((size_t)N*64);
  float* gfb    = alloc((size_t)N*128);                // gate per node
  unsigned char* PV8 = (unsigned char*)alloc((size_t)N*1024);
  unsigned char* QV8 = (unsigned char*)alloc((size_t)N*1024);
  bf16_t* agg   = (bf16_t*)alloc((size_t)N*1856);      // gather out / ys2 / hs / ys1 (in-place chain)
  bf16_t* gate16= (bf16_t*)alloc((size_t)E*64);
  bf16_t* arena = (bf16_t*)alloc(434176);
  int* rowptr = (int*)alloc((size_t)N+8);
  int* curs   = (int*)alloc((size_t)N);
  int* order  = (int*)alloc((size_t)E);
  // total ~185 MB for N=6000, E=120000 (known-good <= 199.5 MB)

  bf16_t* WmsgCT  = arena;            // [4][128][128]
  bf16_t* WvT     = arena + 65536;    // [4][128][64]
  bf16_t* WoT     = arena + 98304;    // [4][128][128]
  bf16_t* Wf1T    = arena + 163840;   // [4][128][128]
  bf16_t* Wf2T    = arena + 229376;   // [4][128][128]
  bf16_t* WapT    = arena + 294912;   // [4][256][64]
  bf16_t* WgT     = arena + 360448;   // [4][128][64]
  bf16_t* WeprojT = arena + 393216;   // [3712][128]

  // CSR by target
  hipMemsetAsync(curs, 0, sizeof(int)*N, stream);
  k_count<<<(E+255)/256, 256, 0, stream>>>(EI, curs, E);
  k_scan<<<1, 1024, 0, stream>>>(curs, rowptr, N);
  k_fill<<<(E+255)/256, 256, 0, stream>>>(EI, curs, order, E);
  k_sort<<<(N+255)/256, 256, 0, stream>>>(rowptr, order, N);

  // weight transposes -> bf16 arenas
  k_tr2<<<256, 256, 0, stream>>>(Wmsg, WmsgCT);
  k_tr<<<128, 256, 0, stream>>>(Wv,   WvT,  4, 64, 128, 8192);
  k_tr<<<256, 256, 0, stream>>>(Wo,   WoT,  4, 128, 128, 16384);
  k_tr<<<256, 256, 0, stream>>>(Wf1,  Wf1T, 4, 128, 128, 16384);
  k_tr<<<256, 256, 0, stream>>>(Wf2,  Wf2T, 4, 128, 128, 16384);
  k_tr<<<256, 256, 0, stream>>>(Wap,  WapT, 4, 64, 256, 16384);
  k_tr<<<128, 256, 0, stream>>>(Wg,   WgT,  4, 64, 128, 8192);
  k_tr<<<1856, 256, 0, stream>>>(Weproj, WeprojT, 1, 128, 3712, 0);

  // radial tables + per-node h2 sum + x init
  k_tab_embed<<<GTAB/4, 256, 0, stream>>>(We0, be0, We1, be1, Wr0, Wr1, Wrl, h2tab, radtab);
  k_h2sum<<<(N+1)/2, 256, 0, stream>>>(ed, h2tab, rowptr, order, h2sum, N);
  k_init_x<<<(N+31)/32, 256, 0, stream>>>(Z, emb, WeprojT, h2sum, Xb, N);

  // layer-0 pqv
  k_pqv<<<N, 512, 0, stream>>>(Xb, gamma1, WmsgCT, WvT, PV8, QV8, P0, Q0, 0);

  const int FB = (N + 3)/4;   // flat blocks (4 nodes each)
  for (int i = 0; i < 4; i++){
    k_edge_logits<<<(E+15)/16, 256, 0, stream>>>(EI, ed, P0, Q0, radtab, WapT, wa, WgT,
                                                 expat, radl, gate16, E, i);
    k_gather<<<N, 512, 0, stream>>>(EI, rowptr, order, PV8, QV8, gate16, expat, radl, agg);
    k_wo  <<<FB, 256, 0, stream>>>(agg, WoT, Xb, gamma2, Wfg, gfb, i, N);
    k_wf1 <<<FB, 256, 0, stream>>>(agg, gfb, Wf1T, i, N);
    k_wf2 <<<FB, 256, 0, stream>>>(agg, Wf2T, Xb, gamma1, i+1, (i < 3) ? 1 : 0, N);
    if (i < 3)
      k_pqnext<<<FB, 256, 0, stream>>>(agg, WmsgCT, WvT, PV8, QV8, P0, Q0, i+1, N);
  }

  int PB = (N+1)/2;
  k_head<<<PB, 256, 0, stream>>>(Xb, Wh1, Wh2, part, N);
  k_reduce<<<1, 256, 0, stream>>>(part, (float*)d_out, PB);
}

// Round 15
// 2048.370 us; speedup vs baseline: 1.1413x; 1.1413x over previous
//
#include <hip/hip_runtime.h>

#define KM 29
#define GTAB 2048

typedef __bf16 bf16_t;
typedef __bf16 bf16x8 __attribute__((ext_vector_type(8)));
typedef __bf16 bf16x4 __attribute__((ext_vector_type(4)));
typedef __bf16 bf16x2 __attribute__((ext_vector_type(2)));
typedef float  f32x4  __attribute__((ext_vector_type(4)));
typedef float  f32x2  __attribute__((ext_vector_type(2)));

__device__ __forceinline__ float silu_f(float x){ return x / (1.0f + __expf(-x)); }

__device__ __forceinline__ float wave_reduce_sum(float v){
  #pragma unroll
  for (int s = 1; s < 64; s <<= 1) v += __shfl_xor(v, s);
  return v;
}

// l-of-k with clamp for pad rows 29..31 (their data is zero)
__device__ __forceinline__ constexpr int LOF2(int k){
  return (k<1)?0 : (k<4)?1 : (k<9)?2 : (k<14)?3 : (k<19)?4 : (k<24)?5 : 6;
}

__device__ __forceinline__ f32x4 mfma16(bf16x8 a, bf16x8 b, f32x4 c){
  return __builtin_amdgcn_mfma_f32_16x16x32_bf16(a, b, c, 0, 0, 0);
}

__device__ __forceinline__ float env_f(float d){
  float xx = d*(1.0f/12.0f);
  float x2 = xx*xx, x4 = x2*x2, x5 = x4*xx;
  float env = 1.0f - 21.0f*x5 + 35.0f*x5*xx - 15.0f*x5*x2;
  return (xx < 1.0f) ? env : 0.0f;
}

// ---------------- CSR build ----------------
__global__ void k_count(const int* __restrict__ EI, int* __restrict__ cnt, int E){
  int e = blockIdx.x*256 + threadIdx.x;
  if (e < E) atomicAdd(&cnt[EI[E+e]], 1);
}

__global__ __launch_bounds__(1024) void k_scan(int* __restrict__ cnt, int* __restrict__ rowptr, int N){
  __shared__ int ts[1024];
  int t = threadIdx.x;
  int base = t*8;
  int loc[8]; int sum = 0;
  #pragma unroll
  for (int u = 0; u < 8; u++){ int idx = base+u; int v = (idx < N) ? cnt[idx] : 0; loc[u] = sum; sum += v; }
  ts[t] = sum; __syncthreads();
  for (int off = 1; off < 1024; off <<= 1){
    int v = (t >= off) ? ts[t-off] : 0;
    __syncthreads();
    ts[t] += v;
    __syncthreads();
  }
  int excl = ts[t] - sum;
  #pragma unroll
  for (int u = 0; u < 8; u++){
    int idx = base+u;
    if (idx < N){ int r = excl + loc[u]; rowptr[idx] = r; cnt[idx] = r; }
  }
  if (t == 1023) rowptr[N] = ts[1023];
}

__global__ void k_fill(const int* __restrict__ EI, int* __restrict__ cur, int* __restrict__ order, int E){
  int e = blockIdx.x*256 + threadIdx.x;
  if (e < E){ int pos = atomicAdd(&cur[EI[E+e]], 1); order[pos] = e; }
}

__global__ void k_sort(const int* __restrict__ rowptr, int* __restrict__ order, int N){
  int n = blockIdx.x*256 + threadIdx.x;
  if (n >= N) return;
  int rp = rowptr[n], re = rowptr[n+1];
  for (int a = rp+1; a < re; a++){
    int key = order[a]; int b = a-1;
    while (b >= rp && order[b] > key){ order[b+1] = order[b]; b--; }
    order[b+1] = key;
  }
}

// ---------------- weight transposes ----------------
__global__ void k_tr(const float* __restrict__ src, bf16_t* __restrict__ dst,
                     int L, int R, int C, int Lstr){
  int idx = blockIdx.x*256 + threadIdx.x;
  int total = L*R*C;
  if (idx >= total) return;
  int l = idx / (R*C); int rem = idx - l*(R*C);
  int r = rem / C; int c = rem - r*C;
  dst[((size_t)l*C + c)*R + r] = (bf16_t)src[(size_t)l*Lstr + (size_t)r*C + c];
}

// Wmsg [4][256][64] -> combined [4][128 cols][128 k]; col<64 = P-half, col>=64 = Q-half
__global__ void k_tr2(const float* __restrict__ src, bf16_t* __restrict__ dst){
  int idx = blockIdx.x*256 + threadIdx.x;
  if (idx >= 4*128*128) return;
  int l = idx >> 14; int j = (idx >> 7) & 127; int c = idx & 127;
  float v = (j < 64) ? src[(size_t)l*16384 + c*64 + j]
                     : src[(size_t)l*16384 + 8192 + c*64 + (j-64)];
  dst[idx] = (bf16_t)v;
}

// ---------------- radial MLP table build ----------------
__global__ __launch_bounds__(256) void k_tab_embed(
    const float* __restrict__ We0, const float* __restrict__ be0,
    const float* __restrict__ We1, const float* __restrict__ be1,
    const float* __restrict__ Wr0, const float* __restrict__ Wr1, const float* __restrict__ Wrl,
    float* __restrict__ h2tab, float* __restrict__ radtab)
{
  __shared__ float sb[4][640];
  const int wid = threadIdx.x >> 6, lane = threadIdx.x & 63;
  const int e = blockIdx.x*4 + wid;
  if (e >= GTAB) return;
  const float d = e * (12.0f/(GTAB-1));
  const float DLT = 12.0f/599.0f;
  const float CO  = -0.5f/((2.0f*DLT)*(2.0f*DLT));
  int jc = (int)(d/DLT + 0.5f);
  int j0 = jc - 16; if (j0 < 0) j0 = 0; if (j0 > 600-32) j0 = 600-32;
  float diff = d - (float)(j0+lane)*DLT;
  float gval = __expf(CO*diff*diff);
  float p[10];
  #pragma unroll
  for (int u = 0; u < 10; u++) p[u] = 0.f;
  const int c2 = 2*lane;
  for (int jj = 0; jj < 32; jj++){
    float gj = __shfl(gval, jj);
    int row = j0 + jj;
    const float2 w0 = *(const float2*)(We0 + row*128 + c2);
    p[0] += gj*w0.x; p[1] += gj*w0.y;
    #pragma unroll
    for (int i = 0; i < 4; i++){
      const float2 wr = *(const float2*)(Wr0 + ((size_t)i*600 + row)*128 + c2);
      p[2+2*i] += gj*wr.x; p[3+2*i] += gj*wr.y;
    }
  }
  sb[wid][c2]   = silu_f(p[0] + be0[c2]);
  sb[wid][c2+1] = silu_f(p[1] + be0[c2+1]);
  #pragma unroll
  for (int i = 0; i < 4; i++){
    sb[wid][128 + 128*i + c2]   = silu_f(p[2+2*i]);
    sb[wid][128 + 128*i + c2+1] = silu_f(p[3+2*i]);
  }
  float a0 = 0.f, a1 = 0.f;
  for (int c = 0; c < 128; c++){
    float hv = sb[wid][c];
    const float2 w = *(const float2*)(We1 + c*128 + c2);
    a0 += hv*w.x; a1 += hv*w.y;
  }
  a0 = silu_f(a0 + be1[c2]); a1 = silu_f(a1 + be1[c2+1]);
  h2tab[(size_t)e*128 + c2]     = a0;
  h2tab[(size_t)e*128 + c2 + 1] = a1;
  #pragma unroll
  for (int i = 0; i < 4; i++){
    float r0 = 0.f, r1 = 0.f;
    const float* W1 = Wr1 + (size_t)i*128*128;
    for (int c = 0; c < 128; c++){
      float rv = sb[wid][128 + 128*i + c];
      const float2 w = *(const float2*)(W1 + c*128 + c2);
      r0 += rv*w.x; r1 += rv*w.y;
    }
    r0 = silu_f(r0); r1 = silu_f(r1);
    const float* Wl = Wrl + (size_t)i*128*7;
    float pl[7];
    #pragma unroll
    for (int l = 0; l < 7; l++) pl[l] = r0*Wl[c2*7+l] + r1*Wl[(c2+1)*7+l];
    #pragma unroll
    for (int l = 0; l < 7; l++) pl[l] = wave_reduce_sum(pl[l]);
    if (lane == 0){
      #pragma unroll
      for (int l = 0; l < 7; l++) radtab[(size_t)e*28 + i*7 + l] = pl[l];
    }
  }
}

// ---------------- per-node h2 sum with inline interp ----------------
__global__ __launch_bounds__(256) void k_h2sum(
    const float* __restrict__ ed, const float* __restrict__ h2tab,
    const int* __restrict__ rowptr, const int* __restrict__ order,
    bf16_t* __restrict__ h2sum, int N)
{
  int n = blockIdx.x*2 + (threadIdx.x >> 7);
  int ch = threadIdx.x & 127;
  if (n >= N) return;
  int rp = rowptr[n], deg = rowptr[n+1] - rp;
  float acc = 0.f;
  for (int idx = 0; idx < deg; idx++){
    int e = order[rp+idx];
    float d = ed[e];
    float u = d * ((GTAB-1)/12.0f);
    int j = (int)u; if (j > GTAB-2) j = GTAB-2;
    float f = u - (float)j;
    float a = h2tab[(size_t)j*128 + ch], b = h2tab[(size_t)(j+1)*128 + ch];
    acc += a + f*(b-a);
  }
  h2sum[(size_t)n*128 + ch] = (bf16_t)acc;
}

// ---------------- x init (MFMA from h2sum) ----------------
__global__ __launch_bounds__(256) void k_init_x(
    const int* __restrict__ Z, const float* __restrict__ emb,
    const bf16_t* __restrict__ WeprojT, const bf16_t* __restrict__ h2sum,
    bf16_t* __restrict__ Xb, int N)
{
  __shared__ bf16_t h2s[32*136];
  __shared__ int Zs[32];
  int n0 = blockIdx.x*32, t = threadIdx.x;
  for (int idx = t; idx < 32*128; idx += 256){
    int nn = idx >> 7, ch = idx & 127;
    int n = n0 + nn;
    h2s[nn*136 + ch] = (n < N) ? h2sum[(size_t)n*128 + ch] : (bf16_t)0.f;
  }
  if (t < 32) Zs[t] = (n0 + t < N) ? Z[n0+t] : 0;
  __syncthreads();
  int wid = t >> 6, lane = t & 63;
  int mtile = wid & 1;
  int row = mtile*16 + (lane & 15);
  int koff = (lane >> 4)*8;
  bf16x8 afr[4];
  #pragma unroll
  for (int kk = 0; kk < 4; kk++) afr[kk] = *(const bf16x8*)(h2s + row*136 + kk*32 + koff);
  for (int nt = (wid>>1); nt < 232; nt += 2){
    f32x4 acc = {0.f,0.f,0.f,0.f};
    int col = nt*16 + (lane & 15);
    #pragma unroll
    for (int kk = 0; kk < 4; kk++){
      bf16x8 b = *(const bf16x8*)(WeprojT + (size_t)col*128 + kk*32 + koff);
      acc = mfma16(afr[kk], b, acc);
    }
    #pragma unroll
    for (int r = 0; r < 4; r++){
      int r32 = mtile*16 + (lane>>4)*4 + r;
      int n = n0 + r32;
      if (n < N){
        float v = acc[r] * (1.0f/23.395238876342773f);
        if (col < 128) v += emb[(size_t)Zs[r32]*128 + col];
        Xb[(size_t)n*3712 + col] = (bf16_t)v;
      }
    }
  }
}

// ---------------- layer-0 pqv: rms + combined [P|Q] GEMM + PV8/QV8 + P0/Q0 ----------------
__global__ __launch_bounds__(512) void k_pqv(
    const bf16_t* __restrict__ Xb, const float* __restrict__ gamma1,
    const bf16_t* __restrict__ WmsgCT, const bf16_t* __restrict__ WvT,
    unsigned char* __restrict__ PV8, unsigned char* __restrict__ QV8,
    float* __restrict__ P0, float* __restrict__ Q0, int layer)
{
  __shared__ bf16_t ys16[32*136];
  __shared__ bf16_t pq16[32*136];
  int n = blockIdx.x, t = threadIdx.x;
  int wid = t >> 6, lane = t & 63;
  const float* g1 = gamma1 + layer*128;
  const bf16_t* xp = Xb + (size_t)n*3712;
  for (int k = wid; k < KM; k += 8){
    float x0 = (float)xp[k*128 + lane], x1 = (float)xp[k*128 + 64 + lane];
    float ss = wave_reduce_sum(x0*x0 + x1*x1);
    float sc = rsqrtf(ss*(1.0f/128.0f) + 1e-6f);
    ys16[k*136 + lane]      = (bf16_t)(x0*sc*g1[lane]);
    ys16[k*136 + 64 + lane] = (bf16_t)(x1*sc*g1[64+lane]);
  }
  for (int idx = t; idx < 3*136; idx += 512) ys16[29*136 + idx] = (bf16_t)0.f;
  __syncthreads();
  int mtile = wid >> 2;
  int row = mtile*16 + (lane & 15);
  int koff = (lane >> 4)*8;
  {
    const bf16_t* Bc = WmsgCT + (size_t)layer*16384;
    f32x4 acc[2] = {{0,0,0,0},{0,0,0,0}};
    #pragma unroll
    for (int kk = 0; kk < 128; kk += 32){
      bf16x8 a = *(const bf16x8*)(ys16 + row*136 + kk + koff);
      #pragma unroll
      for (int u = 0; u < 2; u++){
        int col = ((wid&3)*2+u)*16 + (lane & 15);
        bf16x8 b = *(const bf16x8*)(Bc + (size_t)col*128 + kk + koff);
        acc[u] = mfma16(a, b, acc[u]);
      }
    }
    #pragma unroll
    for (int u = 0; u < 2; u++){
      int col = ((wid&3)*2+u)*16 + (lane & 15);
      #pragma unroll
      for (int r = 0; r < 4; r++){
        int r32 = mtile*16 + (lane>>4)*4 + r;
        pq16[r32*136 + col] = (bf16_t)acc[u][r];
      }
      if (mtile == 0 && (lane>>4) == 0){
        float v = acc[u][0];
        if (col < 64) P0[(size_t)n*64 + col] = v;
        else          Q0[(size_t)n*64 + col - 64] = v;
      }
    }
  }
  __syncthreads();
  {
    const bf16_t* Bt = WvT + (size_t)layer*8192;
    f32x4 accP[2] = {{0,0,0,0},{0,0,0,0}};
    f32x4 accQ[2] = {{0,0,0,0},{0,0,0,0}};
    #pragma unroll
    for (int kk = 0; kk < 64; kk += 32){
      bf16x8 aP = *(const bf16x8*)(pq16 + row*136 + kk + koff);
      bf16x8 aQ = *(const bf16x8*)(pq16 + row*136 + 64 + kk + koff);
      #pragma unroll
      for (int u = 0; u < 2; u++){
        int col = ((wid&3)*2+u)*16 + (lane & 15);
        bf16x8 b = *(const bf16x8*)(Bt + (size_t)col*64 + kk + koff);
        accP[u] = mfma16(aP, b, accP[u]);
        accQ[u] = mfma16(aQ, b, accQ[u]);
      }
    }
    unsigned char* pvp = PV8 + (size_t)n*4096;
    unsigned char* qvp = QV8 + (size_t)n*4096;
    int r0i = mtile*16 + (lane>>4)*4;
    #pragma unroll
    for (int u = 0; u < 2; u++){
      int col = ((wid&3)*2+u)*16 + (lane & 15);
      float pk[4], qk[4];
      #pragma unroll
      for (int r = 0; r < 4; r++){
        int r32 = r0i + r;
        pk[r] = (r32 < KM) ? accP[u][r] : 0.f;
        qk[r] = (r32 < KM) ? accQ[u][r] : 0.f;
      }
      int dw = __builtin_amdgcn_cvt_pk_fp8_f32(pk[0], pk[1], 0, false);
      dw = __builtin_amdgcn_cvt_pk_fp8_f32(pk[2], pk[3], dw, true);
      *(unsigned int*)(pvp + col*32 + r0i) = (unsigned int)dw;
      int dw2 = __builtin_amdgcn_cvt_pk_fp8_f32(qk[0], qk[1], 0, false);
      dw2 = __builtin_amdgcn_cvt_pk_fp8_f32(qk[2], qk[3], dw2, true);
      *(unsigned int*)(qvp + col*32 + r0i) = (unsigned int)dw2;
    }
  }
}

// ---------------- per-layer: edge logits + gate (MFMA); emits expat + radl ----------------
__global__ __launch_bounds__(256) void k_edge_logits(
    const int* __restrict__ EI, const float* __restrict__ ed,
    const float* __restrict__ P0, const float* __restrict__ Q0,
    const float* __restrict__ radtab, const bf16_t* __restrict__ WapT, const float* __restrict__ wa,
    const bf16_t* __restrict__ WgT, float* __restrict__ expat, float* __restrict__ radl,
    bf16_t* __restrict__ gate16, int E, int layer)
{
  __shared__ bf16_t m0s[16*72];
  __shared__ int   srcs[16], tgts[16];
  __shared__ float r0s[16];
  __shared__ float envs[16];
  int t = threadIdx.x;
  int eb = blockIdx.x*16;
  if (t < 16){
    int e = eb + t;
    if (e < E){
      srcs[t] = EI[e]; tgts[t] = EI[E+e];
      float d = ed[e];
      envs[t] = env_f(d);
      float u = d * ((GTAB-1)/12.0f);
      int j = (int)u; if (j > GTAB-2) j = GTAB-2;
      float f = u - (float)j;
      #pragma unroll
      for (int l = 0; l < 7; l++){
        float a = radtab[(size_t)j*28 + layer*7 + l], b = radtab[(size_t)(j+1)*28 + layer*7 + l];
        float rv = a + f*(b-a);
        radl[(size_t)e*7 + l] = rv;
        if (l == 0) r0s[t] = rv;
      }
    } else { srcs[t] = 0; tgts[t] = 0; r0s[t] = 0.f; envs[t] = 0.f; }
  }
  __syncthreads();
  #pragma unroll
  for (int u = 0; u < 4; u++){
    int idx = t + u*256;
    int i = idx >> 6, j = idx & 63;
    m0s[i*72 + j] = (bf16_t)((P0[(size_t)srcs[i]*64 + j] + Q0[(size_t)tgts[i]*64 + j]) * r0s[i]);
  }
  __syncthreads();
  int wid = t >> 6, lane = t & 63;
  int l15 = lane & 15, lg = lane >> 4;
  int koff = lg*8;
  bf16x8 a0 = *(const bf16x8*)(m0s + l15*72 + koff);
  bf16x8 a1 = *(const bf16x8*)(m0s + l15*72 + 32 + koff);
  const bf16_t* Ba = WapT + (size_t)layer*16384;
  const bf16_t* Bg = WgT  + (size_t)layer*8192;
  const float* wav = wa + layer*256;
  f32x4 accA[4], accG[2];
  #pragma unroll
  for (int u = 0; u < 4; u++){
    int col = 64*wid + u*16 + l15;
    f32x4 acc = {0,0,0,0};
    acc = mfma16(a0, *(const bf16x8*)(Ba + (size_t)col*64 + koff), acc);
    acc = mfma16(a1, *(const bf16x8*)(Ba + (size_t)col*64 + 32 + koff), acc);
    accA[u] = acc;
  }
  #pragma unroll
  for (int u = 0; u < 2; u++){
    int col = 32*wid + u*16 + l15;
    f32x4 acc = {0,0,0,0};
    acc = mfma16(a0, *(const bf16x8*)(Bg + (size_t)col*64 + koff), acc);
    acc = mfma16(a1, *(const bf16x8*)(Bg + (size_t)col*64 + 32 + koff), acc);
    accG[u] = acc;
  }
  #pragma unroll
  for (int u = 0; u < 2; u++){
    int col = 32*wid + u*16 + l15;
    #pragma unroll
    for (int r = 0; r < 4; r++){
      int e = eb + lg*4 + r;
      if (e < E) gate16[(size_t)e*128 + col] = (bf16_t)silu_f(accG[u][r]);
    }
  }
  #pragma unroll
  for (int hpair = 0; hpair < 2; hpair++){
    int c0 = 64*wid + hpair*32 + l15;
    float w0 = wav[c0], w1 = wav[c0+16];
    float s[4];
    #pragma unroll
    for (int r = 0; r < 4; r++)
      s[r] = silu_f(accA[2*hpair][r])*w0 + silu_f(accA[2*hpair+1][r])*w1;
    #pragma unroll
    for (int r = 0; r < 4; r++){
      s[r] += __shfl_xor(s[r], 1);
      s[r] += __shfl_xor(s[r], 2);
      s[r] += __shfl_xor(s[r], 4);
      s[r] += __shfl_xor(s[r], 8);
    }
    if (l15 == 0){
      #pragma unroll
      for (int r = 0; r < 4; r++){
        int e = eb + lg*4 + r;
        if (e < E) expat[(size_t)e*8 + 2*wid + hpair] = envs[lg*4 + r] * __expf(s[r]);
      }
    }
  }
}

// fp8 dword -> 4 fp32 FMA into acc
#define FMA_DW(dw, kb) { \
  f32x2 lo_ = __builtin_amdgcn_cvt_pk_f32_fp8((dw), false); \
  f32x2 hi_ = __builtin_amdgcn_cvt_pk_f32_fp8((dw), true); \
  acc[(kb)]   += lo_.x * rw[LOF2((kb))]; \
  acc[(kb)+1] += lo_.y * rw[LOF2((kb)+1)]; \
  acc[(kb)+2] += hi_.x * rw[LOF2((kb)+2)]; \
  acc[(kb)+3] += hi_.y * rw[LOF2((kb)+3)]; }

// ---------------- per-layer: gather-only kernel (1 node per block) ----------------
__global__ __launch_bounds__(512, 4) void k_gather(
    const int* __restrict__ EI, const int* __restrict__ rowptr, const int* __restrict__ order,
    const unsigned char* __restrict__ PV8, const unsigned char* __restrict__ QV8,
    const bf16_t* __restrict__ gate16, const float* __restrict__ expat,
    const float* __restrict__ radl,
    bf16_t* __restrict__ agg)
{
  __shared__ bf16_t mA[32*136];
  __shared__ bf16_t mB[32*136];
  __shared__ float at8[512];
  __shared__ float rl7[512];
  __shared__ int   esb[64], srcs[64];
  __shared__ float denl[32];

  int n = blockIdx.x, t = threadIdx.x;
  int rp = rowptr[n], deg = rowptr[n+1] - rp;
  if (deg == 0){
    for (int idx = t; idx < 3712; idx += 512) agg[(size_t)n*3712 + idx] = (bf16_t)0.f;
    return;
  }
  int eg = t >> 7, hv = t & 127, h = hv >> 4;
  float acc[32];
  #pragma unroll
  for (int j = 0; j < 32; j++) acc[j] = 0.f;
  float S[7];
  #pragma unroll
  for (int l = 0; l < 7; l++) S[l] = 0.f;
  float dpart = 0.f;
  for (int base = 0; base < deg; base += 64){
    int ne = min(64, deg - base);
    if (base > 0) __syncthreads();
    if (t < ne){ int e = order[rp + base + t]; esb[t] = e; srcs[t] = EI[e]; }
    __syncthreads();
    if (t < ne*8){
      int i = t >> 3, q = t & 7;
      int e = esb[i];
      at8[t] = expat[(size_t)e*8 + q];
      if (q < 7) rl7[t] = radl[(size_t)e*7 + q];
    }
    __syncthreads();
    uint4 A0 = {0,0,0,0}, A1 = {0,0,0,0}, B0 = {0,0,0,0}, B1 = {0,0,0,0};
    float gA = 0.f, gB = 0.f;
    int i = eg;
    if (i < ne){
      const uint4* p = (const uint4*)(PV8 + (size_t)srcs[i]*4096 + hv*32);
      A0 = p[0]; A1 = p[1];
      gA = (float)gate16[(size_t)esb[i]*128 + hv];
    }
    if (i + 4 < ne){
      const uint4* p = (const uint4*)(PV8 + (size_t)srcs[i+4]*4096 + hv*32);
      B0 = p[0]; B1 = p[1];
      gB = (float)gate16[(size_t)esb[i+4]*128 + hv];
    }
    while (i < ne){
      int i2 = i + 8;
      uint4 C0 = {0,0,0,0}, C1 = {0,0,0,0}; float gC = 0.f;
      if (i2 < ne){
        const uint4* p = (const uint4*)(PV8 + (size_t)srcs[i2]*4096 + hv*32);
        C0 = p[0]; C1 = p[1];
        gC = (float)gate16[(size_t)esb[i2]*128 + hv];
      }
      float ae = at8[i*8 + h];
      dpart += ae;
      float w = gA * ae;
      float rw[7];
      #pragma unroll
      for (int l = 0; l < 7; l++){ rw[l] = rl7[i*8 + l]*w; S[l] += rw[l]; }
      FMA_DW(A0.x, 0)  FMA_DW(A0.y, 4)  FMA_DW(A0.z, 8)  FMA_DW(A0.w, 12)
      FMA_DW(A1.x, 16) FMA_DW(A1.y, 20) FMA_DW(A1.z, 24) FMA_DW(A1.w, 28)
      A0 = B0; A1 = B1; gA = gB;
      B0 = C0; B1 = C1; gB = gC;
      i += 4;
    }
  }
  {
    const unsigned char* qvp = QV8 + (size_t)n*4096 + hv*32;
    uint4 q0 = *(const uint4*)qvp;
    uint4 q1 = *(const uint4*)(qvp + 16);
    float rw[7];
    #pragma unroll
    for (int l = 0; l < 7; l++) rw[l] = S[l];
    FMA_DW(q0.x, 0)  FMA_DW(q0.y, 4)  FMA_DW(q0.z, 8)  FMA_DW(q0.w, 12)
    FMA_DW(q1.x, 16) FMA_DW(q1.y, 20) FMA_DW(q1.z, 24) FMA_DW(q1.w, 28)
  }
  if ((hv & 15) == 0) denl[eg*8 + h] = dpart;
  __syncthreads();
  {
    float dsum = denl[h] + denl[8 + h] + denl[16 + h] + denl[24 + h];
    float inv = 1.0f/(dsum + 1e-30f);
    #pragma unroll
    for (int j = 0; j < 32; j++) acc[j] *= inv;
  }
  if (eg == 0){
    #pragma unroll
    for (int j = 0; j < 32; j++) mA[j*136 + hv] = (bf16_t)acc[j];
  } else if (eg == 1){
    #pragma unroll
    for (int j = 0; j < 32; j++) mB[j*136 + hv] = (bf16_t)acc[j];
  }
  __syncthreads();
  if (eg == 2){
    #pragma unroll
    for (int j = 0; j < 32; j++) mA[j*136 + hv] = (bf16_t)((float)mA[j*136 + hv] + acc[j]);
  } else if (eg == 3){
    #pragma unroll
    for (int j = 0; j < 32; j++) mB[j*136 + hv] = (bf16_t)((float)mB[j*136 + hv] + acc[j]);
  }
  __syncthreads();
  for (int idx = t; idx < 3712; idx += 512){
    int k = idx >> 7, c = idx & 127;
    agg[(size_t)n*3712 + idx] = (bf16_t)((float)mA[k*136 + c] + (float)mB[k*136 + c]);
  }
}

// ---------------- per-layer: x update (1 node per block, R10/R13 structure) ----------------
__global__ __launch_bounds__(512, 4) void k_xupdate(
    const bf16_t* __restrict__ agg,
    const float* __restrict__ gamma1, const float* __restrict__ gamma2,
    const float* __restrict__ Wfg,
    const bf16_t* __restrict__ Wf1T, const bf16_t* __restrict__ Wf2T,
    const bf16_t* __restrict__ WoT, const bf16_t* __restrict__ WmsgCT, const bf16_t* __restrict__ WvT,
    bf16_t* __restrict__ Xb, int layer,
    unsigned char* __restrict__ PV8o, unsigned char* __restrict__ QV8o,
    float* __restrict__ P0o, float* __restrict__ Q0o, int do_tail, int N)
{
  __shared__ float  xs[3712];
  __shared__ bf16_t ysag[32*136];
  __shared__ bf16_t hsqv[32*136];
  __shared__ float  pf[640];

  int n = blockIdx.x, t = threadIdx.x;
  int wid = t >> 6, lane = t & 63;

  // P0: load x + agg into LDS
  {
    const bf16x2* Xp2 = (const bf16x2*)(Xb + (size_t)n*3712);
    for (int p = t; p < 1856; p += 512){
      bf16x2 v = Xp2[p];
      xs[2*p]   = (float)v.x;
      xs[2*p+1] = (float)v.y;
    }
  }
  for (int idx = t; idx < 3712; idx += 512){
    int k = idx >> 7, c = idx & 127;
    ysag[k*136 + c] = agg[(size_t)n*3712 + idx];
  }
  for (int idx = t; idx < 3*136; idx += 512) ysag[29*136 + idx] = (bf16_t)0.f;
  __syncthreads();
  // P1: Wo GEMM: xs += agg @ WoT
  {
    const bf16_t* Bt = WoT + (size_t)layer*16384;
    int mtile = wid >> 2, colt = (wid & 3)*2;
    int row = mtile*16 + (lane & 15);
    int koff = (lane >> 4)*8;
    f32x4 a2[2] = {{0,0,0,0},{0,0,0,0}};
    #pragma unroll
    for (int kk = 0; kk < 128; kk += 32){
      bf16x8 a = *(const bf16x8*)(ysag + row*136 + kk + koff);
      #pragma unroll
      for (int u = 0; u < 2; u++){
        int col = (colt+u)*16 + (lane & 15);
        bf16x8 b = *(const bf16x8*)(Bt + (size_t)col*128 + kk + koff);
        a2[u] = mfma16(a, b, a2[u]);
      }
    }
    #pragma unroll
    for (int u = 0; u < 2; u++){
      int col = (colt+u)*16 + (lane & 15);
      #pragma unroll
      for (int r = 0; r < 4; r++){
        int r32 = mtile*16 + (lane>>4)*4 + r;
        if (r32 < KM) xs[r32*128 + col] += a2[u][r];
      }
    }
  }
  __syncthreads();
  // P2: rms(gamma2) -> ys
  {
    const float* g2 = gamma2 + layer*128;
    for (int k = wid; k < KM; k += 8){
      float x0 = xs[k*128 + lane], x1 = xs[k*128 + 64 + lane];
      float ss = wave_reduce_sum(x0*x0 + x1*x1);
      float sc = rsqrtf(ss*(1.0f/128.0f) + 1e-6f);
      ysag[k*136 + lane]      = (bf16_t)(x0*sc*g2[lane]);
      ysag[k*136 + 64 + lane] = (bf16_t)(x1*sc*g2[64+lane]);
    }
    for (int idx = t; idx < 3*136; idx += 512) ysag[29*136 + idx] = (bf16_t)0.f;
  }
  __syncthreads();
  // P3: gate partials
  {
    int part = t >> 7, f = t & 127;
    const float* Wfgp = Wfg + (size_t)layer*16384;
    float p = 0.f;
    for (int c = part*32; c < part*32 + 32; c++) p += (float)ysag[c] * Wfgp[c*128 + f];
    pf[part*128 + f] = p;
  }
  __syncthreads();
  if (t < 128) pf[512 + t] = silu_f(pf[t] + pf[128+t] + pf[256+t] + pf[384+t]);
  __syncthreads();
  // P4: Wf1: hs = (ys @ Wf1T) * gf
  {
    const bf16_t* Bt = Wf1T + (size_t)layer*16384;
    int mtile = wid >> 2, colt = (wid & 3)*2;
    int row = mtile*16 + (lane & 15);
    int koff = (lane >> 4)*8;
    f32x4 a2[2] = {{0,0,0,0},{0,0,0,0}};
    #pragma unroll
    for (int kk = 0; kk < 128; kk += 32){
      bf16x8 a = *(const bf16x8*)(ysag + row*136 + kk + koff);
      #pragma unroll
      for (int u = 0; u < 2; u++){
        int col = (colt+u)*16 + (lane & 15);
        bf16x8 b = *(const bf16x8*)(Bt + (size_t)col*128 + kk + koff);
        a2[u] = mfma16(a, b, a2[u]);
      }
    }
    #pragma unroll
    for (int u = 0; u < 2; u++){
      int col = (colt+u)*16 + (lane & 15);
      float gfc = pf[512 + col];
      #pragma unroll
      for (int r = 0; r < 4; r++){
        int r32 = mtile*16 + (lane>>4)*4 + r;
        hsqv[r32*136 + col] = (bf16_t)(a2[u][r]*gfc);
      }
    }
  }
  __syncthreads();
  // P5: Wf2: xs += hs @ Wf2T
  {
    const bf16_t* Bt = Wf2T + (size_t)layer*16384;
    int mtile = wid >> 2, colt = (wid & 3)*2;
    int row = mtile*16 + (lane & 15);
    int koff = (lane >> 4)*8;
    f32x4 a2[2] = {{0,0,0,0},{0,0,0,0}};
    #pragma unroll
    for (int kk = 0; kk < 128; kk += 32){
      bf16x8 a = *(const bf16x8*)(hsqv + row*136 + kk + koff);
      #pragma unroll
      for (int u = 0; u < 2; u++){
        int col = (colt+u)*16 + (lane & 15);
        bf16x8 b = *(const bf16x8*)(Bt + (size_t)col*128 + kk + koff);
        a2[u] = mfma16(a, b, a2[u]);
      }
    }
    #pragma unroll
    for (int u = 0; u < 2; u++){
      int col = (colt+u)*16 + (lane & 15);
      #pragma unroll
      for (int r = 0; r < 4; r++){
        int r32 = mtile*16 + (lane>>4)*4 + r;
        if (r32 < KM) xs[r32*128 + col] += a2[u][r];
      }
    }
  }
  __syncthreads();
  // P6: store x
  {
    bf16x2* Xp2 = (bf16x2*)(Xb + (size_t)n*3712);
    for (int p = t; p < 1856; p += 512){
      bf16x2 v;
      v.x = (bf16_t)xs[2*p];
      v.y = (bf16_t)xs[2*p+1];
      Xp2[p] = v;
    }
  }
  if (!do_tail) return;
  // P7: rms(gamma1[next]) -> ys
  {
    const float* g1n = gamma1 + (size_t)(layer+1)*128;
    for (int k = wid; k < KM; k += 8){
      float x0 = xs[k*128 + lane], x1 = xs[k*128 + 64 + lane];
      float ss = wave_reduce_sum(x0*x0 + x1*x1);
      float sc = rsqrtf(ss*(1.0f/128.0f) + 1e-6f);
      ysag[k*136 + lane]      = (bf16_t)(x0*sc*g1n[lane]);
      ysag[k*136 + 64 + lane] = (bf16_t)(x1*sc*g1n[64+lane]);
    }
  }
  __syncthreads();
  {
    int mtile = wid >> 2;
    int row = mtile*16 + (lane & 15);
    int koff = (lane >> 4)*8;
    // P8: pq = ys @ WmsgCT[next] -> hsqv; P0o/Q0o from row 0
    {
      const bf16_t* Bc = WmsgCT + (size_t)(layer+1)*16384;
      f32x4 acc[2] = {{0,0,0,0},{0,0,0,0}};
      #pragma unroll
      for (int kk = 0; kk < 128; kk += 32){
        bf16x8 a = *(const bf16x8*)(ysag + row*136 + kk + koff);
        #pragma unroll
        for (int u = 0; u < 2; u++){
          int col = ((wid&3)*2+u)*16 + (lane & 15);
          bf16x8 b = *(const bf16x8*)(Bc + (size_t)col*128 + kk + koff);
          acc[u] = mfma16(a, b, acc[u]);
        }
      }
      #pragma unroll
      for (int u = 0; u < 2; u++){
        int col = ((wid&3)*2+u)*16 + (lane & 15);
        #pragma unroll
        for (int r = 0; r < 4; r++){
          int r32 = mtile*16 + (lane>>4)*4 + r;
          hsqv[r32*136 + col] = (bf16_t)acc[u][r];
        }
        if (mtile == 0 && ((lane>>4) == 0)){
          float v = acc[u][0];
          if (col < 64) P0o[(size_t)n*64 + col] = v;
          else          Q0o[(size_t)n*64 + col - 64] = v;
        }
      }
    }
    __syncthreads();
    // P9: PV8o/QV8o = pq[:,0:64]/pq[:,64:128] @ WvT[next]
    {
      const bf16_t* Bt = WvT + (size_t)(layer+1)*8192;
      f32x4 accP[2] = {{0,0,0,0},{0,0,0,0}};
      f32x4 accQ[2] = {{0,0,0,0},{0,0,0,0}};
      #pragma unroll
      for (int kk = 0; kk < 64; kk += 32){
        bf16x8 aP = *(const bf16x8*)(hsqv + row*136 + kk + koff);
        bf16x8 aQ = *(const bf16x8*)(hsqv + row*136 + 64 + kk + koff);
        #pragma unroll
        for (int u = 0; u < 2; u++){
          int col = ((wid&3)*2+u)*16 + (lane & 15);
          bf16x8 b = *(const bf16x8*)(Bt + (size_t)col*64 + kk + koff);
          accP[u] = mfma16(aP, b, accP[u]);
          accQ[u] = mfma16(aQ, b, accQ[u]);
        }
      }
      unsigned char* pvp = PV8o + (size_t)n*4096;
      unsigned char* qvp = QV8o + (size_t)n*4096;
      int r0i = mtile*16 + (lane>>4)*4;
      #pragma unroll
      for (int u = 0; u < 2; u++){
        int col = ((wid&3)*2+u)*16 + (lane & 15);
        float pk[4], qk[4];
        #pragma unroll
        for (int r = 0; r < 4; r++){
          int r32 = r0i + r;
          pk[r] = (r32 < KM) ? accP[u][r] : 0.f;
          qk[r] = (r32 < KM) ? accQ[u][r] : 0.f;
        }
        int dw = __builtin_amdgcn_cvt_pk_fp8_f32(pk[0], pk[1], 0, false);
        dw = __builtin_amdgcn_cvt_pk_fp8_f32(pk[2], pk[3], dw, true);
        *(unsigned int*)(pvp + col*32 + r0i) = (unsigned int)dw;
        int dw2 = __builtin_amdgcn_cvt_pk_fp8_f32(qk[0], qk[1], 0, false);
        dw2 = __builtin_amdgcn_cvt_pk_fp8_f32(qk[2], qk[3], dw2, true);
        *(unsigned int*)(qvp + col*32 + r0i) = (unsigned int)dw2;
      }
    }
  }
}

// ---------------- output head ----------------
__global__ __launch_bounds__(256) void k_head(
    const bf16_t* __restrict__ Xb, const float* __restrict__ Wh1, const float* __restrict__ Wh2,
    float* __restrict__ partial, int N)
{
  __shared__ float wsum[4];
  int t = threadIdx.x;
  int half = t >> 7;
  int n = blockIdx.x*2 + half;
  int f = t & 127;
  float sv = 0.f;
  if (n < N){
    const bf16_t* xp = Xb + (size_t)n*3712;
    float acc = 0.f;
    for (int c = 0; c < 128; c++) acc += (float)xp[c]*Wh1[c*128 + f];
    sv = silu_f(acc)*Wh2[f];
  }
  sv = wave_reduce_sum(sv);
  if ((t & 63) == 0) wsum[t >> 6] = sv;
  __syncthreads();
  if (t == 0) partial[blockIdx.x] = wsum[0] + wsum[1] + wsum[2] + wsum[3];
}

__global__ __launch_bounds__(256) void k_reduce(const float* __restrict__ partial, float* __restrict__ out, int P){
  __shared__ float sh[256];
  int t = threadIdx.x;
  float s = 0.f;
  for (int i = t; i < P; i += 256) s += partial[i];
  sh[t] = s; __syncthreads();
  for (int off = 128; off > 0; off >>= 1){
    if (t < off) sh[t] += sh[t+off];
    __syncthreads();
  }
  if (t == 0) out[0] = sh[0] / 77.81317f;
}

extern "C" void kernel_launch(void* const* d_in, const int* in_sizes, int n_in,
                              void* d_out, int out_size, void* d_ws, size_t ws_size,
                              hipStream_t stream)
{
  const int*   Z      = (const int*)d_in[0];
  const int*   EI     = (const int*)d_in[1];
  const float* ed     = (const float*)d_in[2];
  const float* emb    = (const float*)d_in[3];
  const float* We0    = (const float*)d_in[4];
  const float* be0    = (const float*)d_in[5];
  const float* We1    = (const float*)d_in[6];
  const float* be1    = (const float*)d_in[7];
  const float* Weproj = (const float*)d_in[8];
  const float* gamma1 = (const float*)d_in[9];
  const float* gamma2 = (const float*)d_in[10];
  const float* Wr0    = (const float*)d_in[11];
  const float* Wr1    = (const float*)d_in[12];
  const float* Wrl    = (const float*)d_in[13];
  const float* Wmsg   = (const float*)d_in[14];
  const float* Wap    = (const float*)d_in[15];
  const float* wa     = (const float*)d_in[16];
  const float* Wg     = (const float*)d_in[17];
  const float* Wv     = (const float*)d_in[18];
  const float* Wo     = (const float*)d_in[19];
  const float* Wf1    = (const float*)d_in[20];
  const float* Wfg    = (const float*)d_in[21];
  const float* Wf2    = (const float*)d_in[22];
  const float* Wh1    = (const float*)d_in[23];
  const float* Wh2    = (const float*)d_in[24];

  const int N = in_sizes[0];
  const int E = in_sizes[2];

  float* ws = (float*)d_ws;
  size_t o = 0;
  auto alloc = [&](size_t nf){ float* p = ws + o; o += (nf + 7) & ~(size_t)7; return p; };

  bf16_t* Xb    = (bf16_t*)alloc((size_t)N*1856);      // N*3712 bf16
  float* P0     = alloc((size_t)N*64);
  float* Q0     = alloc((size_t)N*64);
  float* expat  = alloc((size_t)E*8);
  float* radl   = alloc((size_t)E*7);
  float* part   = alloc((size_t)((N+1)/2) + 8);
  float* radtab = alloc((size_t)GTAB*28);
  float* h2tab  = alloc((size_t)GTAB*128);
  bf16_t* h2sum = (bf16_t*)alloc((size_t)N*64);        // N*128 bf16
  unsigned char* PV8 = (unsigned char*)alloc((size_t)N*1024);  // N*4096 fp8
  unsigned char* QV8 = (unsigned char*)alloc((size_t)N*1024);  // N*4096 fp8
  bf16_t* agg   = (bf16_t*)alloc((size_t)N*1856);      // N*3712 bf16
  bf16_t* gate16= (bf16_t*)alloc((size_t)E*64);        // E*128 bf16
  bf16_t* arena = (bf16_t*)alloc(434176);              // 868352 bf16
  int* rowptr = (int*)alloc((size_t)N+8);
  int* curs   = (int*)alloc((size_t)N);
  int* order  = (int*)alloc((size_t)E);
  // total ~182 MB for N=6000, E=120000 (known-good <= 199.5 MB)

  bf16_t* WmsgCT  = arena;            // [4][128][128]
  bf16_t* WvT     = arena + 65536;    // [4][128][64]
  bf16_t* WoT     = arena + 98304;    // [4][128][128]
  bf16_t* Wf1T    = arena + 163840;   // [4][128][128]
  bf16_t* Wf2T    = arena + 229376;   // [4][128][128]
  bf16_t* WapT    = arena + 294912;   // [4][256][64]
  bf16_t* WgT     = arena + 360448;   // [4][128][64]
  bf16_t* WeprojT = arena + 393216;   // [3712][128]

  // CSR by target
  hipMemsetAsync(curs, 0, sizeof(int)*N, stream);
  k_count<<<(E+255)/256, 256, 0, stream>>>(EI, curs, E);
  k_scan<<<1, 1024, 0, stream>>>(curs, rowptr, N);
  k_fill<<<(E+255)/256, 256, 0, stream>>>(EI, curs, order, E);
  k_sort<<<(N+255)/256, 256, 0, stream>>>(rowptr, order, N);

  // weight transposes -> bf16 arenas
  k_tr2<<<256, 256, 0, stream>>>(Wmsg, WmsgCT);
  k_tr<<<128, 256, 0, stream>>>(Wv,   WvT,  4, 64, 128, 8192);
  k_tr<<<256, 256, 0, stream>>>(Wo,   WoT,  4, 128, 128, 16384);
  k_tr<<<256, 256, 0, stream>>>(Wf1,  Wf1T, 4, 128, 128, 16384);
  k_tr<<<256, 256, 0, stream>>>(Wf2,  Wf2T, 4, 128, 128, 16384);
  k_tr<<<256, 256, 0, stream>>>(Wap,  WapT, 4, 64, 256, 16384);
  k_tr<<<128, 256, 0, stream>>>(Wg,   WgT,  4, 64, 128, 8192);
  k_tr<<<1856, 256, 0, stream>>>(Weproj, WeprojT, 1, 128, 3712, 0);

  // radial tables + per-node h2 sum (inline interp) + x init
  k_tab_embed<<<GTAB/4, 256, 0, stream>>>(We0, be0, We1, be1, Wr0, Wr1, Wrl, h2tab, radtab);
  k_h2sum<<<(N+1)/2, 256, 0, stream>>>(ed, h2tab, rowptr, order, h2sum, N);
  k_init_x<<<(N+31)/32, 256, 0, stream>>>(Z, emb, WeprojT, h2sum, Xb, N);

  // layer-0 pqv (later layers' pqv fused into k_xupdate tail)
  k_pqv<<<N, 512, 0, stream>>>(Xb, gamma1, WmsgCT, WvT, PV8, QV8, P0, Q0, 0);

  for (int i = 0; i < 4; i++){
    k_edge_logits<<<(E+15)/16, 256, 0, stream>>>(EI, ed, P0, Q0, radtab, WapT, wa, WgT,
                                                 expat, radl, gate16, E, i);
    k_gather<<<N, 512, 0, stream>>>(EI, rowptr, order, PV8, QV8, gate16, expat, radl, agg);
    k_xupdate<<<N, 512, 0, stream>>>(agg, gamma1, gamma2, Wfg, Wf1T, Wf2T, WoT, WmsgCT, WvT,
                                     Xb, i, PV8, QV8, P0, Q0, (i < 3) ? 1 : 0, N);
  }

  int PB = (N+1)/2;
  k_head<<<PB, 256, 0, stream>>>(Xb, Wh1, Wh2, part, N);
  k_reduce<<<1, 256, 0, stream>>>(part, (float*)d_out, PB);
}